// Round 1
// baseline (911.585 us; speedup 1.0000x reference)
//
#include <hip/hip_runtime.h>
#include <math.h>

#define NEG_SLOPE 0.2f

__device__ __forceinline__ float lrelu(float x){ return x > 0.f ? x : NEG_SLOPE * x; }
__device__ __forceinline__ float elu_f(float x){ return x > 0.f ? x : __expf(x) - 1.f; }

// ---------------- CSR build ----------------
__global__ void hist_kernel(const int* __restrict__ dst, int E, int N, int* counts){
  int i = blockIdx.x * 256 + threadIdx.x;
  if (i < E + N){
    int d = (i < E) ? dst[i] : (i - E);
    atomicAdd(&counts[d], 1);
  }
}

__global__ void scan_kernel(const int* __restrict__ counts, int* __restrict__ row_ptr, int N){
  __shared__ int s[1024];
  __shared__ int carry_s;
  int tid = threadIdx.x;
  if (tid == 0) carry_s = 0;
  __syncthreads();
  for (int base = 0; base < N; base += 1024){
    int i = base + tid;
    int v = (i < N) ? counts[i] : 0;
    s[tid] = v;
    __syncthreads();
    for (int off = 1; off < 1024; off <<= 1){
      int t = (tid >= off) ? s[tid - off] : 0;
      __syncthreads();
      s[tid] += t;
      __syncthreads();
    }
    if (i < N) row_ptr[i] = carry_s + s[tid] - v;   // exclusive
    __syncthreads();
    if (tid == 1023) carry_s += s[1023];
    __syncthreads();
  }
  if (tid == 0) row_ptr[N] = carry_s;
}

__global__ void cursor_init(const int* __restrict__ rp, int* __restrict__ cur, int N){
  int i = blockIdx.x * 256 + threadIdx.x;
  if (i < N) cur[i] = rp[i];
}

__global__ void scatter_kernel(const int* __restrict__ src, const int* __restrict__ dst,
                               int E, int N, int* cursor, int* __restrict__ edge_src){
  int i = blockIdx.x * 256 + threadIdx.x;
  if (i < E + N){
    int s, d;
    if (i < E){ s = src[i]; d = dst[i]; }
    else      { s = i - E;  d = i - E;  }
    int pos = atomicAdd(&cursor[d], 1);
    edge_src[pos] = s;
  }
}

// ---------------- GEMM: C[N,M] = A[N,K] @ B[K,M], f32 ----------------
__global__ __launch_bounds__(256) void gemm_kernel(const float* __restrict__ A,
                                                   const float* __restrict__ B,
                                                   float* __restrict__ C,
                                                   int N, int K, int M){
  __shared__ float As[16][65];  // [k][row]
  __shared__ float Bs[16][65];  // [k][col]
  int tx = threadIdx.x & 15, ty = threadIdx.x >> 4;
  int row0 = blockIdx.y * 64, col0 = blockIdx.x * 64;
  float acc[4][4] = {};
  for (int k0 = 0; k0 < K; k0 += 16){
#pragma unroll
    for (int q = 0; q < 4; q++){
      int idx = threadIdx.x + q * 256;
      int r = idx >> 4, c = idx & 15;
      int row = row0 + r;
      As[c][r] = (row < N) ? A[(size_t)row * K + k0 + c] : 0.f;
    }
#pragma unroll
    for (int q = 0; q < 4; q++){
      int idx = threadIdx.x + q * 256;
      int r = idx >> 6, c = idx & 63;
      Bs[r][c] = B[(size_t)(k0 + r) * M + col0 + c];
    }
    __syncthreads();
#pragma unroll
    for (int kk = 0; kk < 16; kk++){
      float a[4], b[4];
#pragma unroll
      for (int i = 0; i < 4; i++) a[i] = As[kk][ty * 4 + i];
#pragma unroll
      for (int j = 0; j < 4; j++) b[j] = Bs[kk][tx * 4 + j];
#pragma unroll
      for (int i = 0; i < 4; i++)
#pragma unroll
        for (int j = 0; j < 4; j++)
          acc[i][j] += a[i] * b[j];
    }
    __syncthreads();
  }
#pragma unroll
  for (int i = 0; i < 4; i++){
    int row = row0 + ty * 4 + i;
    if (row < N){
#pragma unroll
      for (int j = 0; j < 4; j++)
        C[(size_t)row * M + col0 + tx * 4 + j] = acc[i][j];
    }
  }
}

// ---------------- attention logits: al[n,h] = sum_c h[n,h,c]*a[h,c] ----------------
template<int H>
__global__ void al_kernel(const float* __restrict__ hb, const float* __restrict__ asrc,
                          const float* __restrict__ adst,
                          float* __restrict__ als, float* __restrict__ ald, int N){
  int n = blockIdx.x;
  int t = threadIdx.x;  // H*64 threads
  float v = hb[(size_t)n * (H * 64) + t];
  float ps = v * asrc[t];
  float pd = v * adst[t];
#pragma unroll
  for (int off = 32; off > 0; off >>= 1){
    ps += __shfl_down(ps, off);
    pd += __shfl_down(pd, off);
  }
  if ((t & 63) == 0){
    als[n * H + (t >> 6)] = ps;
    ald[n * H + (t >> 6)] = pd;
  }
}

// ---------------- per-dst-node softmax + aggregate (one wave per node) ----------------
template<int H, int CPL>
__global__ __launch_bounds__(256) void agg_kernel(const float* __restrict__ hb,
    const float* __restrict__ als, const float* __restrict__ ald,
    const int* __restrict__ row_ptr, const int* __restrict__ edge_src,
    const float* __restrict__ bias, float* __restrict__ out, int N){
  const int HC = 64 * CPL;
  int node = (blockIdx.x * 256 + threadIdx.x) >> 6;
  int lane = threadIdx.x & 63;
  if (node >= N) return;
  int beg = row_ptr[node], end = row_ptr[node + 1];

  float adv[H];
  if (H == 4){
    float4 t = *(const float4*)(ald + node * 4);
    adv[0] = t.x; adv[1] = t.y; adv[2] = t.z; adv[3] = t.w;
  } else {
    adv[0] = ald[node];
  }

  // pass 1: per-head max over all incoming edges (lanes stride edges)
  float mx[H];
#pragma unroll
  for (int h = 0; h < H; h++) mx[h] = -1e30f;
  for (int j = beg + lane; j < end; j += 64){
    int u = edge_src[j];
    if (H == 4){
      float4 t = *(const float4*)(als + u * 4);
      mx[0] = fmaxf(mx[0], lrelu(t.x + adv[0]));
      mx[1] = fmaxf(mx[1], lrelu(t.y + adv[1]));
      mx[2] = fmaxf(mx[2], lrelu(t.z + adv[2]));
      mx[3] = fmaxf(mx[3], lrelu(t.w + adv[3]));
    } else {
      mx[0] = fmaxf(mx[0], lrelu(als[u] + adv[0]));
    }
  }
#pragma unroll
  for (int off = 32; off > 0; off >>= 1)
#pragma unroll
    for (int h = 0; h < H; h++) mx[h] = fmaxf(mx[h], __shfl_xor(mx[h], off));

  const int hh = (lane * CPL) >> 6;  // this lane's head
  float mh = mx[hh];
  float advh = adv[hh];

  // pass 2: denom + weighted feature accumulation (whole wave per edge)
  float acc[CPL];
#pragma unroll
  for (int k = 0; k < CPL; k++) acc[k] = 0.f;
  float denom = 0.f;
  const float* hbl = hb + lane * CPL;
  for (int j = beg; j < end; j++){
    int u = edge_src[j];
    float e = lrelu(als[u * H + hh] + advh);
    float ex = __expf(e - mh);
    denom += ex;
    const float* hp = hbl + (size_t)u * HC;
    if (CPL == 4){
      float4 t = *(const float4*)hp;
      acc[0] += ex * t.x; acc[1] += ex * t.y; acc[2] += ex * t.z; acc[3] += ex * t.w;
    } else {
      acc[0] += ex * hp[0];
    }
  }
  float inv = 1.f / (denom + 1e-16f);
#pragma unroll
  for (int k = 0; k < CPL; k++){
    int ch = lane * CPL + k;
    float o = acc[k] * inv + bias[ch];
    out[(size_t)node * HC + ch] = elu_f(o);
  }
}

// ---------------- pooling (batch sorted) ----------------
__global__ void pool_kernel(const float* __restrict__ f, const int* __restrict__ batch,
                            float* sums, int* cnts, int N){
  int lane = threadIdx.x;  // block of 64
  int s = blockIdx.x * 128;
  if (s >= N) return;
  int e = min(s + 128, N);
  float acc = 0.f;
  int cnt = 0;
  int cur = batch[s];
  for (int n = s; n < e; n++){
    int g = batch[n];
    if (g != cur){
      atomicAdd(&sums[cur * 64 + lane], acc);
      if (lane == 0) atomicAdd(&cnts[cur], cnt);
      acc = 0.f; cnt = 0; cur = g;
    }
    acc += f[(size_t)n * 64 + lane];
    cnt++;
  }
  atomicAdd(&sums[cur * 64 + lane], acc);
  if (lane == 0) atomicAdd(&cnts[cur], cnt);
}

__global__ void final_kernel(const float* __restrict__ sums, const int* __restrict__ cnts,
                             const float* __restrict__ linW, const float* __restrict__ linb,
                             float* __restrict__ out){
  int t = threadIdx.x;
  if (t >= 640) return;
  int g = t / 10, o = t % 10;
  float c = fmaxf((float)cnts[g], 1.f);
  float acc = 0.f;
#pragma unroll
  for (int k = 0; k < 64; k++) acc += sums[g * 64 + k] * linW[k * 10 + o];
  out[t] = acc / c + linb[o];
}

// ---------------- launch ----------------
extern "C" void kernel_launch(void* const* d_in, const int* in_sizes, int n_in,
                              void* d_out, int out_size, void* d_ws, size_t ws_size,
                              hipStream_t stream) {
  const float* x     = (const float*)d_in[0];
  const int*   ei    = (const int*)  d_in[1];
  const int*   batch = (const int*)  d_in[2];
  const float* W1    = (const float*)d_in[3];
  const float* b1    = (const float*)d_in[4];
  const float* asrc1 = (const float*)d_in[5];
  const float* adst1 = (const float*)d_in[6];
  const float* W2    = (const float*)d_in[7];
  const float* b2    = (const float*)d_in[8];
  const float* asrc2 = (const float*)d_in[9];
  const float* adst2 = (const float*)d_in[10];
  const float* W3    = (const float*)d_in[11];
  const float* b3    = (const float*)d_in[12];
  const float* asrc3 = (const float*)d_in[13];
  const float* adst3 = (const float*)d_in[14];
  const float* linW  = (const float*)d_in[15];
  const float* linb  = (const float*)d_in[16];

  const int N = in_sizes[0] / 128;   // 50000
  const int E = in_sizes[1] / 2;     // 600000
  const int Etot = E + N;
  const int G = 64;
  const int* src = ei;
  const int* dst = ei + E;

  // workspace carve (256B aligned)
  char* p = (char*)d_ws;
  auto carve = [&](size_t bytes) -> char* {
    char* r = p;
    p += (bytes + 255) & ~(size_t)255;
    return r;
  };
  float* hbuf     = (float*)carve((size_t)N * 256 * 4);
  float* featA    = (float*)carve((size_t)N * 256 * 4);
  float* als      = (float*)carve((size_t)N * 4 * 4);
  float* ald      = (float*)carve((size_t)N * 4 * 4);
  int*   counts   = (int*)  carve((size_t)N * 4);
  int*   row_ptr  = (int*)  carve((size_t)(N + 1) * 4);
  int*   cursor   = (int*)  carve((size_t)N * 4);
  int*   edge_src = (int*)  carve((size_t)Etot * 4);
  float* sums     = (float*)carve((size_t)G * 64 * 4);
  int*   cnts     = (int*)  carve((size_t)G * 4);

  // ---- CSR build ----
  hipMemsetAsync(counts, 0, (size_t)N * 4, stream);
  hist_kernel<<<(Etot + 255) / 256, 256, 0, stream>>>(dst, E, N, counts);
  scan_kernel<<<1, 1024, 0, stream>>>(counts, row_ptr, N);
  cursor_init<<<(N + 255) / 256, 256, 0, stream>>>(row_ptr, cursor, N);
  scatter_kernel<<<(Etot + 255) / 256, 256, 0, stream>>>(src, dst, E, N, cursor, edge_src);

  dim3 gemm_block(256);
  int nb_rows = (N + 63) / 64;
  int agg_grid = (N + 3) / 4;

  // ---- layer 1: 128 -> 4x64 ----
  gemm_kernel<<<dim3(256 / 64, nb_rows), gemm_block, 0, stream>>>(x, W1, hbuf, N, 128, 256);
  al_kernel<4><<<N, 256, 0, stream>>>(hbuf, asrc1, adst1, als, ald, N);
  agg_kernel<4, 4><<<agg_grid, 256, 0, stream>>>(hbuf, als, ald, row_ptr, edge_src, b1, featA, N);

  // ---- layer 2: 256 -> 4x64 ----
  gemm_kernel<<<dim3(256 / 64, nb_rows), gemm_block, 0, stream>>>(featA, W2, hbuf, N, 256, 256);
  al_kernel<4><<<N, 256, 0, stream>>>(hbuf, asrc2, adst2, als, ald, N);
  agg_kernel<4, 4><<<agg_grid, 256, 0, stream>>>(hbuf, als, ald, row_ptr, edge_src, b2, featA, N);

  // ---- layer 3: 256 -> 1x64 ----
  gemm_kernel<<<dim3(64 / 64, nb_rows), gemm_block, 0, stream>>>(featA, W3, hbuf, N, 256, 64);
  al_kernel<1><<<N, 64, 0, stream>>>(hbuf, asrc3, adst3, als, ald, N);
  agg_kernel<1, 1><<<agg_grid, 256, 0, stream>>>(hbuf, als, ald, row_ptr, edge_src, b3, featA, N);

  // ---- pool + final linear ----
  hipMemsetAsync(sums, 0, (size_t)G * 64 * 4, stream);
  hipMemsetAsync(cnts, 0, (size_t)G * 4, stream);
  pool_kernel<<<(N + 127) / 128, 64, 0, stream>>>(featA, batch, sums, cnts, N);
  final_kernel<<<1, 640, 0, stream>>>(sums, cnts, linW, linb, (float*)d_out);
}

// Round 2
// 569.051 us; speedup vs baseline: 1.6019x; 1.6019x over previous
//
#include <hip/hip_runtime.h>
#include <hip/hip_bf16.h>
#include <math.h>

#define NEG_SLOPE 0.2f

typedef short short8 __attribute__((ext_vector_type(8)));
typedef float f32x4 __attribute__((ext_vector_type(4)));
typedef unsigned int u32;
typedef unsigned short u16;

__device__ __forceinline__ float lrelu(float x){ return x > 0.f ? x : NEG_SLOPE * x; }
__device__ __forceinline__ float elu_f(float x){ return x > 0.f ? x : __expf(x) - 1.f; }
__device__ __forceinline__ float bf2f(u16 u){ return __uint_as_float(((u32)u) << 16); }
__device__ __forceinline__ u16 f2bf(float f){
  __hip_bfloat16 h = __float2bfloat16(f);
  return *(u16*)&h;
}

// ---------------- dtype conversion ----------------
__global__ void cvt_bf16_kernel(const float* __restrict__ in, u16* __restrict__ out, int n4){
  int i = blockIdx.x * 256 + threadIdx.x;
  if (i < n4){
    float4 v = ((const float4*)in)[i];
    ushort4 o;
    o.x = f2bf(v.x); o.y = f2bf(v.y); o.z = f2bf(v.z); o.w = f2bf(v.w);
    ((ushort4*)out)[i] = o;
  }
}

// W[k][m] f32 -> Wt[m][k] bf16
__global__ void transpose_w_kernel(const float* __restrict__ W, u16* __restrict__ Wt, int K, int M){
  int i = blockIdx.x * 256 + threadIdx.x;
  if (i < K * M){
    int k = i / M, m = i % M;
    Wt[m * K + k] = f2bf(W[i]);
  }
}

// ---------------- CSR build ----------------
__global__ void hist_kernel(const int* __restrict__ dst, int E, int N, int* counts){
  int i = blockIdx.x * 256 + threadIdx.x;
  if (i < E + N){
    int d = (i < E) ? dst[i] : (i - E);
    atomicAdd(&counts[d], 1);
  }
}

__global__ void scan_block_kernel(const int* __restrict__ counts, int* __restrict__ rp,
                                  int* __restrict__ bsums, int N){
  __shared__ int s[256];
  int i = blockIdx.x * 256 + threadIdx.x;
  int v = (i < N) ? counts[i] : 0;
  s[threadIdx.x] = v;
  __syncthreads();
  for (int off = 1; off < 256; off <<= 1){
    int t = (threadIdx.x >= off) ? s[threadIdx.x - off] : 0;
    __syncthreads();
    s[threadIdx.x] += t;
    __syncthreads();
  }
  if (i < N) rp[i] = s[threadIdx.x] - v;          // block-local exclusive
  if (threadIdx.x == 255) bsums[blockIdx.x] = s[255];
}

__global__ void scan_sums_kernel(int* bsums, int nb, int* total){
  __shared__ int s[256];
  int v = (threadIdx.x < nb) ? bsums[threadIdx.x] : 0;
  s[threadIdx.x] = v;
  __syncthreads();
  for (int off = 1; off < 256; off <<= 1){
    int t = (threadIdx.x >= off) ? s[threadIdx.x - off] : 0;
    __syncthreads();
    s[threadIdx.x] += t;
    __syncthreads();
  }
  if (threadIdx.x < nb) bsums[threadIdx.x] = s[threadIdx.x] - v;  // exclusive
  if (threadIdx.x == 255) *total = s[255];
}

__global__ void scan_add_kernel(int* __restrict__ rp, const int* __restrict__ bsums,
                                const int* __restrict__ total, int N){
  int i = blockIdx.x * 256 + threadIdx.x;
  if (i < N) rp[i] += bsums[blockIdx.x];
  if (i == 0) rp[N] = *total;
}

__global__ void cursor_init(const int* __restrict__ rp, int* __restrict__ cur, int N){
  int i = blockIdx.x * 256 + threadIdx.x;
  if (i < N) cur[i] = rp[i];
}

__global__ void scatter_kernel(const int* __restrict__ src, const int* __restrict__ dst,
                               int E, int N, int* cursor, int* __restrict__ edge_src){
  int i = blockIdx.x * 256 + threadIdx.x;
  if (i < E + N){
    int s, d;
    if (i < E){ s = src[i]; d = dst[i]; }
    else      { s = i - E;  d = i - E;  }
    int pos = atomicAdd(&cursor[d], 1);
    edge_src[pos] = s;
  }
}

// ---------------- bf16 MFMA GEMM: C[N,M] = A[N,K] @ Bt[M,K]^T ----------------
// BM=128, BK=64 (8 chunks of 8 bf16 = 16B). LDS chunk-major: [chunk][row][8].
template<int BN>
__global__ __launch_bounds__(256) void gemm_mfma(const u16* __restrict__ A,
                                                 const u16* __restrict__ Bt,
                                                 u16* __restrict__ C,
                                                 int N, int K, int M){
  constexpr int BM = 128;
  constexpr int MI = (BN == 128) ? 4 : 2;
  constexpr int SB = BN * 8 / 256;
  __shared__ short As[8][BM][8];
  __shared__ short Bs[8][BN][8];
  const int tid = threadIdx.x;
  const int w = tid >> 6, lane = tid & 63;
  const int quad = lane >> 4, l16 = lane & 15;
  const int row0 = blockIdx.y * BM, col0 = blockIdx.x * BN;
  const int wrow = (BN == 128) ? (w >> 1) * 64 : w * 32;
  const int wcol = (BN == 128) ? (w & 1) * 64 : 0;

  f32x4 acc[MI][4];
#pragma unroll
  for (int i = 0; i < MI; i++)
#pragma unroll
    for (int j = 0; j < 4; j++) acc[i][j] = (f32x4){0.f, 0.f, 0.f, 0.f};

  for (int k0 = 0; k0 < K; k0 += 64){
    __syncthreads();
#pragma unroll
    for (int q = 0; q < 4; q++){
      int lb = q * 256 + w * 64;      // wave-uniform
      int li = lb + lane;
      int c = li >> 7, r = li & 127;
      int grow = min(row0 + r, N - 1);
      const u16* gp = A + (size_t)grow * K + k0 + c * 8;
      __builtin_amdgcn_global_load_lds((const __attribute__((address_space(1))) void*)gp,
                                       (__attribute__((address_space(3))) void*)((char*)&As[0][0][0] + (size_t)lb * 16),
                                       16, 0, 0);
    }
#pragma unroll
    for (int q = 0; q < SB; q++){
      int lb = q * 256 + w * 64;
      int li = lb + lane;
      int c = li / BN, n = li % BN;
      const u16* gp = Bt + (size_t)(col0 + n) * K + k0 + c * 8;
      __builtin_amdgcn_global_load_lds((const __attribute__((address_space(1))) void*)gp,
                                       (__attribute__((address_space(3))) void*)((char*)&Bs[0][0][0] + (size_t)lb * 16),
                                       16, 0, 0);
    }
    __syncthreads();
#pragma unroll
    for (int ks = 0; ks < 2; ks++){
      short8 a[MI], b[4];
#pragma unroll
      for (int i = 0; i < MI; i++) a[i] = *(const short8*)&As[ks * 4 + quad][wrow + i * 16 + l16][0];
#pragma unroll
      for (int j = 0; j < 4; j++)  b[j] = *(const short8*)&Bs[ks * 4 + quad][wcol + j * 16 + l16][0];
#pragma unroll
      for (int i = 0; i < MI; i++)
#pragma unroll
        for (int j = 0; j < 4; j++)
          acc[i][j] = __builtin_amdgcn_mfma_f32_16x16x32_bf16(a[i], b[j], acc[i][j], 0, 0, 0);
    }
  }
  // epilogue: D layout col=lane&15, row=quad*4+reg
#pragma unroll
  for (int i = 0; i < MI; i++){
#pragma unroll
    for (int rr = 0; rr < 4; rr++){
      int row = row0 + wrow + i * 16 + quad * 4 + rr;
      if (row < N){
#pragma unroll
        for (int j = 0; j < 4; j++)
          C[(size_t)row * M + col0 + wcol + j * 16 + l16] = f2bf(acc[i][j][rr]);
      }
    }
  }
}

// ---------------- attention logits ----------------
template<int H>
__global__ void al_kernel(const u16* __restrict__ hb, const float* __restrict__ asrc,
                          const float* __restrict__ adst,
                          float* __restrict__ als, float* __restrict__ ald, int N){
  int n = blockIdx.x;
  int t = threadIdx.x;  // H*64 threads
  float v = bf2f(hb[(size_t)n * (H * 64) + t]);
  float ps = v * asrc[t];
  float pd = v * adst[t];
#pragma unroll
  for (int off = 32; off > 0; off >>= 1){
    ps += __shfl_down(ps, off);
    pd += __shfl_down(pd, off);
  }
  if ((t & 63) == 0){
    als[n * H + (t >> 6)] = ps;
    ald[n * H + (t >> 6)] = pd;
  }
}

// ---------------- per-dst softmax + aggregate, bf16 features ----------------
template<int H, bool OBF>
__global__ __launch_bounds__(256) void agg_kernel(const u16* __restrict__ hb,
    const float* __restrict__ als, const float* __restrict__ ald,
    const int* __restrict__ row_ptr, const int* __restrict__ edge_src,
    const float* __restrict__ bias, void* __restrict__ outv, int N){
  int node = (blockIdx.x * 256 + threadIdx.x) >> 6;
  int lane = threadIdx.x & 63;
  if (node >= N) return;
  int beg = row_ptr[node], end = row_ptr[node + 1];

  if (H == 4){
    float4 t4 = *(const float4*)(ald + node * 4);
    float adv0 = t4.x, adv1 = t4.y, adv2 = t4.z, adv3 = t4.w;
    float m0 = -1e30f, m1 = -1e30f, m2 = -1e30f, m3 = -1e30f;
    for (int j = beg + lane; j < end; j += 64){
      int u = edge_src[j];
      float4 s = *(const float4*)(als + u * 4);
      m0 = fmaxf(m0, lrelu(s.x + adv0));
      m1 = fmaxf(m1, lrelu(s.y + adv1));
      m2 = fmaxf(m2, lrelu(s.z + adv2));
      m3 = fmaxf(m3, lrelu(s.w + adv3));
    }
#pragma unroll
    for (int off = 32; off > 0; off >>= 1){
      m0 = fmaxf(m0, __shfl_xor(m0, off));
      m1 = fmaxf(m1, __shfl_xor(m1, off));
      m2 = fmaxf(m2, __shfl_xor(m2, off));
      m3 = fmaxf(m3, __shfl_xor(m3, off));
    }
    int hh = lane >> 4;
    float mh   = (hh == 0) ? m0 : (hh == 1) ? m1 : (hh == 2) ? m2 : m3;
    float advh = (hh == 0) ? adv0 : (hh == 1) ? adv1 : (hh == 2) ? adv2 : adv3;
    float a0 = 0.f, a1 = 0.f, a2 = 0.f, a3 = 0.f, denom = 0.f;
    const u16* hbl = hb + lane * 4;
    for (int j = beg; j < end; j++){
      int u = edge_src[j];
      float e = lrelu(als[u * 4 + hh] + advh);
      float ex = __expf(e - mh);
      denom += ex;
      uint2 t = *(const uint2*)(hbl + (size_t)u * 256);
      a0 += ex * __uint_as_float((t.x & 0xffffu) << 16);
      a1 += ex * __uint_as_float(t.x & 0xffff0000u);
      a2 += ex * __uint_as_float((t.y & 0xffffu) << 16);
      a3 += ex * __uint_as_float(t.y & 0xffff0000u);
    }
    float inv = 1.f / (denom + 1e-16f);
    int ch = lane * 4;
    float o0 = elu_f(a0 * inv + bias[ch]);
    float o1 = elu_f(a1 * inv + bias[ch + 1]);
    float o2 = elu_f(a2 * inv + bias[ch + 2]);
    float o3 = elu_f(a3 * inv + bias[ch + 3]);
    if (OBF){
      uint2 o;
      o.x = (u32)f2bf(o0) | ((u32)f2bf(o1) << 16);
      o.y = (u32)f2bf(o2) | ((u32)f2bf(o3) << 16);
      ((uint2*)outv)[(size_t)node * 64 + lane] = o;
    } else {
      float4 o = make_float4(o0, o1, o2, o3);
      *(float4*)((float*)outv + (size_t)node * 256 + ch) = o;
    }
  } else {
    float adv0 = ald[node];
    float m0 = -1e30f;
    for (int j = beg + lane; j < end; j += 64){
      m0 = fmaxf(m0, lrelu(als[edge_src[j]] + adv0));
    }
#pragma unroll
    for (int off = 32; off > 0; off >>= 1) m0 = fmaxf(m0, __shfl_xor(m0, off));
    // two edges per iteration: lanes 0-31 edge j, lanes 32-63 edge j+1; 2 ch/lane
    int eo = lane >> 5;
    int chb = (lane & 31) * 2;
    float a0 = 0.f, a1 = 0.f, denom = 0.f;
    for (int j = beg; j < end; j += 2){
      int jj = j + eo;
      bool valid = jj < end;
      int u = valid ? edge_src[jj] : 0;
      float e = lrelu(als[u] + adv0);
      float ex = valid ? __expf(e - m0) : 0.f;
      denom += ex;
      u32 t = valid ? *(const u32*)(hb + (size_t)u * 64 + chb) : 0u;
      a0 += ex * __uint_as_float((t & 0xffffu) << 16);
      a1 += ex * __uint_as_float(t & 0xffff0000u);
    }
    denom += __shfl_xor(denom, 32);
    a0 += __shfl_xor(a0, 32);
    a1 += __shfl_xor(a1, 32);
    if (eo == 0){
      float inv = 1.f / (denom + 1e-16f);
      float o0 = elu_f(a0 * inv + bias[chb]);
      float o1 = elu_f(a1 * inv + bias[chb + 1]);
      *(float2*)((float*)outv + (size_t)node * 64 + chb) = make_float2(o0, o1);
    }
  }
}

// ---------------- pooling (batch sorted) ----------------
__global__ void pool_kernel(const float* __restrict__ f, const int* __restrict__ batch,
                            float* sums, int* cnts, int N){
  int lane = threadIdx.x;  // block of 64
  int s = blockIdx.x * 128;
  if (s >= N) return;
  int e = min(s + 128, N);
  float acc = 0.f;
  int cnt = 0;
  int cur = batch[s];
  for (int n = s; n < e; n++){
    int g = batch[n];
    if (g != cur){
      atomicAdd(&sums[cur * 64 + lane], acc);
      if (lane == 0) atomicAdd(&cnts[cur], cnt);
      acc = 0.f; cnt = 0; cur = g;
    }
    acc += f[(size_t)n * 64 + lane];
    cnt++;
  }
  atomicAdd(&sums[cur * 64 + lane], acc);
  if (lane == 0) atomicAdd(&cnts[cur], cnt);
}

__global__ void final_kernel(const float* __restrict__ sums, const int* __restrict__ cnts,
                             const float* __restrict__ linW, const float* __restrict__ linb,
                             float* __restrict__ out){
  int t = threadIdx.x;
  if (t >= 640) return;
  int g = t / 10, o = t % 10;
  float c = fmaxf((float)cnts[g], 1.f);
  float acc = 0.f;
#pragma unroll
  for (int k = 0; k < 64; k++) acc += sums[g * 64 + k] * linW[k * 10 + o];
  out[t] = acc / c + linb[o];
}

// ---------------- launch ----------------
extern "C" void kernel_launch(void* const* d_in, const int* in_sizes, int n_in,
                              void* d_out, int out_size, void* d_ws, size_t ws_size,
                              hipStream_t stream) {
  const float* x     = (const float*)d_in[0];
  const int*   ei    = (const int*)  d_in[1];
  const int*   batch = (const int*)  d_in[2];
  const float* W1    = (const float*)d_in[3];
  const float* b1    = (const float*)d_in[4];
  const float* asrc1 = (const float*)d_in[5];
  const float* adst1 = (const float*)d_in[6];
  const float* W2    = (const float*)d_in[7];
  const float* b2    = (const float*)d_in[8];
  const float* asrc2 = (const float*)d_in[9];
  const float* adst2 = (const float*)d_in[10];
  const float* W3    = (const float*)d_in[11];
  const float* b3    = (const float*)d_in[12];
  const float* asrc3 = (const float*)d_in[13];
  const float* adst3 = (const float*)d_in[14];
  const float* linW  = (const float*)d_in[15];
  const float* linb  = (const float*)d_in[16];

  const int N = in_sizes[0] / 128;   // 50000
  const int E = in_sizes[1] / 2;     // 600000
  const int Etot = E + N;
  const int G = 64;
  const int* src = ei;
  const int* dst = ei + E;

  char* p = (char*)d_ws;
  auto carve = [&](size_t bytes) -> char* {
    char* r = p;
    p += (bytes + 255) & ~(size_t)255;
    return r;
  };
  u16*   xb       = (u16*)  carve((size_t)N * 128 * 2);
  u16*   w1t      = (u16*)  carve((size_t)256 * 128 * 2);
  u16*   w2t      = (u16*)  carve((size_t)256 * 256 * 2);
  u16*   w3t      = (u16*)  carve((size_t)64 * 256 * 2);
  u16*   hb       = (u16*)  carve((size_t)N * 256 * 2);
  u16*   featb    = (u16*)  carve((size_t)N * 256 * 2);
  float* out3     = (float*)carve((size_t)N * 64 * 4);
  float* als      = (float*)carve((size_t)N * 4 * 4);
  float* ald      = (float*)carve((size_t)N * 4 * 4);
  int*   counts   = (int*)  carve((size_t)N * 4);
  int*   row_ptr  = (int*)  carve((size_t)(N + 1) * 4);
  int*   cursor   = (int*)  carve((size_t)N * 4);
  int*   edge_src = (int*)  carve((size_t)Etot * 4);
  int*   bsums    = (int*)  carve(256 * 4);
  int*   total    = (int*)  carve(256);
  float* sums     = (float*)carve((size_t)G * 64 * 4);
  int*   cnts     = (int*)  carve((size_t)G * 4);

  const int nb = (N + 255) / 256;   // 196

  // ---- conversions ----
  cvt_bf16_kernel<<<(N * 128 / 4 + 255) / 256, 256, 0, stream>>>(x, xb, N * 128 / 4);
  transpose_w_kernel<<<(128 * 256 + 255) / 256, 256, 0, stream>>>(W1, w1t, 128, 256);
  transpose_w_kernel<<<(256 * 256 + 255) / 256, 256, 0, stream>>>(W2, w2t, 256, 256);
  transpose_w_kernel<<<(256 * 64 + 255) / 256, 256, 0, stream>>>(W3, w3t, 256, 64);

  // ---- CSR build ----
  hipMemsetAsync(counts, 0, (size_t)N * 4, stream);
  hist_kernel<<<(Etot + 255) / 256, 256, 0, stream>>>(dst, E, N, counts);
  scan_block_kernel<<<nb, 256, 0, stream>>>(counts, row_ptr, bsums, N);
  scan_sums_kernel<<<1, 256, 0, stream>>>(bsums, nb, total);
  scan_add_kernel<<<nb, 256, 0, stream>>>(row_ptr, bsums, total, N);
  cursor_init<<<(N + 255) / 256, 256, 0, stream>>>(row_ptr, cursor, N);
  scatter_kernel<<<(Etot + 255) / 256, 256, 0, stream>>>(src, dst, E, N, cursor, edge_src);

  const int nby = (N + 127) / 128;  // 391 row tiles
  const int agg_grid = (N + 3) / 4;

  // ---- layer 1: 128 -> 4x64 ----
  gemm_mfma<128><<<dim3(2, nby), 256, 0, stream>>>(xb, w1t, hb, N, 128, 256);
  al_kernel<4><<<N, 256, 0, stream>>>(hb, asrc1, adst1, als, ald, N);
  agg_kernel<4, true><<<agg_grid, 256, 0, stream>>>(hb, als, ald, row_ptr, edge_src, b1, featb, N);

  // ---- layer 2: 256 -> 4x64 ----
  gemm_mfma<128><<<dim3(2, nby), 256, 0, stream>>>(featb, w2t, hb, N, 256, 256);
  al_kernel<4><<<N, 256, 0, stream>>>(hb, asrc2, adst2, als, ald, N);
  agg_kernel<4, true><<<agg_grid, 256, 0, stream>>>(hb, als, ald, row_ptr, edge_src, b2, featb, N);

  // ---- layer 3: 256 -> 1x64 ----
  gemm_mfma<64><<<dim3(1, nby), 256, 0, stream>>>(featb, w3t, hb, N, 256, 64);
  al_kernel<1><<<N, 64, 0, stream>>>(hb, asrc3, adst3, als, ald, N);
  agg_kernel<1, false><<<agg_grid, 256, 0, stream>>>(hb, als, ald, row_ptr, edge_src, b3, out3, N);

  // ---- pool + final linear ----
  hipMemsetAsync(sums, 0, (size_t)G * 64 * 4, stream);
  hipMemsetAsync(cnts, 0, (size_t)G * 4, stream);
  pool_kernel<<<(N + 127) / 128, 64, 0, stream>>>(out3, batch, sums, cnts, N);
  final_kernel<<<1, 640, 0, stream>>>(sums, cnts, linW, linb, (float*)d_out);
}

// Round 3
// 432.867 us; speedup vs baseline: 2.1059x; 1.3146x over previous
//
#include <hip/hip_runtime.h>
#include <hip/hip_bf16.h>
#include <math.h>

#define NEG_SLOPE 0.2f

typedef short short8 __attribute__((ext_vector_type(8)));
typedef float f32x4 __attribute__((ext_vector_type(4)));
typedef unsigned int u32;
typedef unsigned short u16;

__device__ __forceinline__ float lrelu(float x){ return x > 0.f ? x : NEG_SLOPE * x; }
__device__ __forceinline__ float elu_f(float x){ return x > 0.f ? x : __expf(x) - 1.f; }
__device__ __forceinline__ float bf2f(u16 u){ return __uint_as_float(((u32)u) << 16); }
__device__ __forceinline__ u16 f2bf(float f){
  __hip_bfloat16 h = __float2bfloat16(f);
  return *(u16*)&h;
}

// ---------------- dtype conversion ----------------
__global__ void cvt_bf16_kernel(const float* __restrict__ in, u16* __restrict__ out, int n4){
  int i = blockIdx.x * 256 + threadIdx.x;
  if (i < n4){
    float4 v = ((const float4*)in)[i];
    ushort4 o;
    o.x = f2bf(v.x); o.y = f2bf(v.y); o.z = f2bf(v.z); o.w = f2bf(v.w);
    ((ushort4*)out)[i] = o;
  }
}

// W[k][m] f32 -> Wt[m][k] bf16
__global__ void transpose_w_kernel(const float* __restrict__ W, u16* __restrict__ Wt, int K, int M){
  int i = blockIdx.x * 256 + threadIdx.x;
  if (i < K * M){
    int k = i / M, m = i % M;
    Wt[m * K + k] = f2bf(W[i]);
  }
}

// ---------------- CSR build ----------------
__global__ void hist_kernel(const int* __restrict__ dst, int E, int N, int* counts){
  int i = blockIdx.x * 256 + threadIdx.x;
  if (i < E + N){
    int d = (i < E) ? dst[i] : (i - E);
    atomicAdd(&counts[d], 1);
  }
}

__global__ void scan_block_kernel(const int* __restrict__ counts, int* __restrict__ rp,
                                  int* __restrict__ bsums, int N){
  __shared__ int s[256];
  int i = blockIdx.x * 256 + threadIdx.x;
  int v = (i < N) ? counts[i] : 0;
  s[threadIdx.x] = v;
  __syncthreads();
  for (int off = 1; off < 256; off <<= 1){
    int t = (threadIdx.x >= off) ? s[threadIdx.x - off] : 0;
    __syncthreads();
    s[threadIdx.x] += t;
    __syncthreads();
  }
  if (i < N) rp[i] = s[threadIdx.x] - v;          // block-local exclusive
  if (threadIdx.x == 255) bsums[blockIdx.x] = s[255];
}

__global__ void scan_sums_kernel(int* bsums, int nb, int* total){
  __shared__ int s[256];
  int v = (threadIdx.x < nb) ? bsums[threadIdx.x] : 0;
  s[threadIdx.x] = v;
  __syncthreads();
  for (int off = 1; off < 256; off <<= 1){
    int t = (threadIdx.x >= off) ? s[threadIdx.x - off] : 0;
    __syncthreads();
    s[threadIdx.x] += t;
    __syncthreads();
  }
  if (threadIdx.x < nb) bsums[threadIdx.x] = s[threadIdx.x] - v;  // exclusive
  if (threadIdx.x == 255) *total = s[255];
}

__global__ void scan_add_kernel(int* __restrict__ rp, int* __restrict__ cur,
                                const int* __restrict__ bsums,
                                const int* __restrict__ total, int N){
  int i = blockIdx.x * 256 + threadIdx.x;
  if (i < N){
    int v = rp[i] + bsums[blockIdx.x];
    rp[i] = v;
    cur[i] = v;
  }
  if (i == 0) rp[N] = *total;
}

__global__ void scatter_kernel(const int* __restrict__ src, const int* __restrict__ dst,
                               int E, int N, int* cursor, int* __restrict__ edge_src){
  int i = blockIdx.x * 256 + threadIdx.x;
  if (i < E + N){
    int s, d;
    if (i < E){ s = src[i]; d = dst[i]; }
    else      { s = i - E;  d = i - E;  }
    int pos = atomicAdd(&cursor[d], 1);
    edge_src[pos] = s;
  }
}

// ---------------- bf16 MFMA GEMM: C[N,M] = A[N,K] @ Bt[M,K]^T ----------------
template<int BN>
__global__ __launch_bounds__(256) void gemm_mfma(const u16* __restrict__ A,
                                                 const u16* __restrict__ Bt,
                                                 u16* __restrict__ C,
                                                 int N, int K, int M){
  constexpr int BM = 128;
  constexpr int MI = (BN == 128) ? 4 : 2;
  constexpr int SB = BN * 8 / 256;
  __shared__ short As[8][BM][8];
  __shared__ short Bs[8][BN][8];
  const int tid = threadIdx.x;
  const int w = tid >> 6, lane = tid & 63;
  const int quad = lane >> 4, l16 = lane & 15;
  const int row0 = blockIdx.y * BM, col0 = blockIdx.x * BN;
  const int wrow = (BN == 128) ? (w >> 1) * 64 : w * 32;
  const int wcol = (BN == 128) ? (w & 1) * 64 : 0;

  f32x4 acc[MI][4];
#pragma unroll
  for (int i = 0; i < MI; i++)
#pragma unroll
    for (int j = 0; j < 4; j++) acc[i][j] = (f32x4){0.f, 0.f, 0.f, 0.f};

  for (int k0 = 0; k0 < K; k0 += 64){
    __syncthreads();
#pragma unroll
    for (int q = 0; q < 4; q++){
      int lb = q * 256 + w * 64;      // wave-uniform
      int li = lb + lane;
      int c = li >> 7, r = li & 127;
      int grow = min(row0 + r, N - 1);
      const u16* gp = A + (size_t)grow * K + k0 + c * 8;
      __builtin_amdgcn_global_load_lds((const __attribute__((address_space(1))) void*)gp,
                                       (__attribute__((address_space(3))) void*)((char*)&As[0][0][0] + (size_t)lb * 16),
                                       16, 0, 0);
    }
#pragma unroll
    for (int q = 0; q < SB; q++){
      int lb = q * 256 + w * 64;
      int li = lb + lane;
      int c = li / BN, n = li % BN;
      const u16* gp = Bt + (size_t)(col0 + n) * K + k0 + c * 8;
      __builtin_amdgcn_global_load_lds((const __attribute__((address_space(1))) void*)gp,
                                       (__attribute__((address_space(3))) void*)((char*)&Bs[0][0][0] + (size_t)lb * 16),
                                       16, 0, 0);
    }
    __syncthreads();
#pragma unroll
    for (int ks = 0; ks < 2; ks++){
      short8 a[MI], b[4];
#pragma unroll
      for (int i = 0; i < MI; i++) a[i] = *(const short8*)&As[ks * 4 + quad][wrow + i * 16 + l16][0];
#pragma unroll
      for (int j = 0; j < 4; j++)  b[j] = *(const short8*)&Bs[ks * 4 + quad][wcol + j * 16 + l16][0];
#pragma unroll
      for (int i = 0; i < MI; i++)
#pragma unroll
        for (int j = 0; j < 4; j++)
          acc[i][j] = __builtin_amdgcn_mfma_f32_16x16x32_bf16(a[i], b[j], acc[i][j], 0, 0, 0);
    }
  }
#pragma unroll
  for (int i = 0; i < MI; i++){
#pragma unroll
    for (int rr = 0; rr < 4; rr++){
      int row = row0 + wrow + i * 16 + quad * 4 + rr;
      if (row < N){
#pragma unroll
        for (int j = 0; j < 4; j++)
          C[(size_t)row * M + col0 + wcol + j * 16 + l16] = f2bf(acc[i][j][rr]);
      }
    }
  }
}

// ---------------- attention logits (wave per node) ----------------
template<int H>
__global__ __launch_bounds__(256) void al_kernel(const u16* __restrict__ hb,
                          const float* __restrict__ asrc, const float* __restrict__ adst,
                          float* __restrict__ als, float* __restrict__ ald, int N){
  int node = (blockIdx.x * 256 + threadIdx.x) >> 6;
  int lane = threadIdx.x & 63;
  if (node >= N) return;
  if (H == 4){
    float4 as = *(const float4*)(asrc + lane * 4);
    float4 ad = *(const float4*)(adst + lane * 4);
    uint2 t = *(const uint2*)(hb + (size_t)node * 256 + lane * 4);
    float v0 = __uint_as_float((t.x & 0xffffu) << 16);
    float v1 = __uint_as_float(t.x & 0xffff0000u);
    float v2 = __uint_as_float((t.y & 0xffffu) << 16);
    float v3 = __uint_as_float(t.y & 0xffff0000u);
    float ps = v0 * as.x + v1 * as.y + v2 * as.z + v3 * as.w;
    float pd = v0 * ad.x + v1 * ad.y + v2 * ad.z + v3 * ad.w;
#pragma unroll
    for (int off = 8; off > 0; off >>= 1){
      ps += __shfl_xor(ps, off);
      pd += __shfl_xor(pd, off);
    }
    if ((lane & 15) == 0){
      als[node * 4 + (lane >> 4)] = ps;
      ald[node * 4 + (lane >> 4)] = pd;
    }
  } else {
    float v = bf2f(hb[(size_t)node * 64 + lane]);
    float ps = v * asrc[lane];
    float pd = v * adst[lane];
#pragma unroll
    for (int off = 32; off > 0; off >>= 1){
      ps += __shfl_xor(ps, off);
      pd += __shfl_xor(pd, off);
    }
    if (lane == 0){
      als[node] = ps;
      ald[node] = pd;
    }
  }
}

// ---------------- H=4 aggregate: lane-parallel ex precompute + broadcast loop ----------------
template<bool OBF>
__global__ __launch_bounds__(256) void agg4_kernel(const u16* __restrict__ hb,
    const float* __restrict__ als, const float* __restrict__ ald,
    const int* __restrict__ row_ptr, const int* __restrict__ edge_src,
    const float* __restrict__ bias, void* __restrict__ outv, int N){
  __shared__ float lex[4][256];
  __shared__ int lu[4][64];
  int wslot = threadIdx.x >> 6;
  int node = (blockIdx.x * 256 + threadIdx.x) >> 6;
  int lane = threadIdx.x & 63;
  if (node >= N) return;
  int beg = row_ptr[node], end = row_ptr[node + 1];
  int deg = end - beg;
  float4 t4 = *(const float4*)(ald + node * 4);

  // lane-parallel: logits + per-head max (cache first chunk)
  float m0 = -1e30f, m1 = -1e30f, m2 = -1e30f, m3 = -1e30f;
  int u_mine = 0;
  float e0 = -1e30f, e1 = -1e30f, e2 = -1e30f, e3 = -1e30f;
  for (int c0 = 0; c0 < deg; c0 += 64){
    int j = c0 + lane;
    bool v = j < deg;
    int u = v ? edge_src[beg + j] : 0;
    float4 s = v ? *(const float4*)(als + (size_t)u * 4)
                 : make_float4(-1e30f, -1e30f, -1e30f, -1e30f);
    float f0 = lrelu(s.x + t4.x), f1 = lrelu(s.y + t4.y);
    float f2 = lrelu(s.z + t4.z), f3 = lrelu(s.w + t4.w);
    m0 = fmaxf(m0, f0); m1 = fmaxf(m1, f1);
    m2 = fmaxf(m2, f2); m3 = fmaxf(m3, f3);
    if (c0 == 0){ u_mine = u; e0 = f0; e1 = f1; e2 = f2; e3 = f3; }
  }
#pragma unroll
  for (int off = 32; off > 0; off >>= 1){
    m0 = fmaxf(m0, __shfl_xor(m0, off)); m1 = fmaxf(m1, __shfl_xor(m1, off));
    m2 = fmaxf(m2, __shfl_xor(m2, off)); m3 = fmaxf(m3, __shfl_xor(m3, off));
  }
  const int hh = lane >> 4;
  float a0 = 0.f, a1 = 0.f, a2 = 0.f, a3 = 0.f, denom = 0.f;
  const u16* hbl = hb + lane * 4;

  for (int c0 = 0; c0 < deg; c0 += 64){
    int cnt = min(64, deg - c0);
    int u; float f0, f1, f2, f3;
    if (c0 == 0){ u = u_mine; f0 = e0; f1 = e1; f2 = e2; f3 = e3; }
    else {
      int j = c0 + lane;
      bool v = j < deg;
      u = v ? edge_src[beg + j] : 0;
      float4 s = v ? *(const float4*)(als + (size_t)u * 4)
                   : make_float4(-1e30f, -1e30f, -1e30f, -1e30f);
      f0 = lrelu(s.x + t4.x); f1 = lrelu(s.y + t4.y);
      f2 = lrelu(s.z + t4.z); f3 = lrelu(s.w + t4.w);
    }
    float4 exv;
    exv.x = __expf(f0 - m0); exv.y = __expf(f1 - m1);
    exv.z = __expf(f2 - m2); exv.w = __expf(f3 - m3);
    *(float4*)&lex[wslot][lane * 4] = exv;
    lu[wslot][lane] = u;
    asm volatile("s_waitcnt lgkmcnt(0)" ::: "memory");
#pragma unroll 4
    for (int j = 0; j < cnt; j++){
      float ex = lex[wslot][j * 4 + hh];   // broadcast ds_read
      int uu = lu[wslot][j];               // broadcast ds_read
      uint2 t = *(const uint2*)(hbl + (size_t)uu * 256);
      denom += ex;
      a0 += ex * __uint_as_float((t.x & 0xffffu) << 16);
      a1 += ex * __uint_as_float(t.x & 0xffff0000u);
      a2 += ex * __uint_as_float((t.y & 0xffffu) << 16);
      a3 += ex * __uint_as_float(t.y & 0xffff0000u);
    }
    asm volatile("" ::: "memory");
  }
  float inv = 1.f / (denom + 1e-16f);
  int ch = lane * 4;
  float o0 = elu_f(a0 * inv + bias[ch]);
  float o1 = elu_f(a1 * inv + bias[ch + 1]);
  float o2 = elu_f(a2 * inv + bias[ch + 2]);
  float o3 = elu_f(a3 * inv + bias[ch + 3]);
  if (OBF){
    uint2 o;
    o.x = (u32)f2bf(o0) | ((u32)f2bf(o1) << 16);
    o.y = (u32)f2bf(o2) | ((u32)f2bf(o3) << 16);
    ((uint2*)outv)[(size_t)node * 64 + lane] = o;
  } else {
    *(float4*)((float*)outv + (size_t)node * 256 + ch) = make_float4(o0, o1, o2, o3);
  }
}

// ---------------- H=1 aggregate ----------------
__global__ __launch_bounds__(256) void agg1_kernel(const u16* __restrict__ hb,
    const float* __restrict__ als, const float* __restrict__ ald,
    const int* __restrict__ row_ptr, const int* __restrict__ edge_src,
    const float* __restrict__ bias, float* __restrict__ out, int N){
  __shared__ float lex[4][64];
  __shared__ int lu[4][64];
  int wslot = threadIdx.x >> 6;
  int node = (blockIdx.x * 256 + threadIdx.x) >> 6;
  int lane = threadIdx.x & 63;
  if (node >= N) return;
  int beg = row_ptr[node], end = row_ptr[node + 1];
  int deg = end - beg;
  float adv = ald[node];
  float m = -1e30f;
  int u_mine = 0; float e_mine = -1e30f;
  for (int c0 = 0; c0 < deg; c0 += 64){
    int j = c0 + lane;
    bool v = j < deg;
    int u = v ? edge_src[beg + j] : 0;
    float e = v ? lrelu(als[u] + adv) : -1e30f;
    m = fmaxf(m, e);
    if (c0 == 0){ u_mine = u; e_mine = e; }
  }
#pragma unroll
  for (int off = 32; off > 0; off >>= 1) m = fmaxf(m, __shfl_xor(m, off));
  int eo = lane >> 5;
  int chb = (lane & 31) * 2;
  float a0 = 0.f, a1 = 0.f, denom = 0.f;
  for (int c0 = 0; c0 < deg; c0 += 64){
    int cnt = min(64, deg - c0);
    int u; float e;
    if (c0 == 0){ u = u_mine; e = e_mine; }
    else {
      int j = c0 + lane;
      bool v = j < deg;
      u = v ? edge_src[beg + j] : 0;
      e = v ? lrelu(als[u] + adv) : -1e30f;
    }
    lex[wslot][lane] = __expf(e - m);
    lu[wslot][lane] = u;
    asm volatile("s_waitcnt lgkmcnt(0)" ::: "memory");
#pragma unroll 4
    for (int j = 0; j < cnt; j += 2){
      int jj = j + eo;
      bool valid = jj < cnt;
      float ex = valid ? lex[wslot][jj] : 0.f;
      int uu = valid ? lu[wslot][jj] : 0;
      u32 t = *(const u32*)(hb + (size_t)uu * 64 + chb);
      denom += ex;
      a0 += ex * __uint_as_float((t & 0xffffu) << 16);
      a1 += ex * __uint_as_float(t & 0xffff0000u);
    }
    asm volatile("" ::: "memory");
  }
  denom += __shfl_xor(denom, 32);
  a0 += __shfl_xor(a0, 32);
  a1 += __shfl_xor(a1, 32);
  if (eo == 0){
    float inv = 1.f / (denom + 1e-16f);
    out[(size_t)node * 64 + chb]     = elu_f(a0 * inv + bias[chb]);
    out[(size_t)node * 64 + chb + 1] = elu_f(a1 * inv + bias[chb + 1]);
  }
}

// ---------------- pooling (batch sorted) ----------------
__global__ void pool_kernel(const float* __restrict__ f, const int* __restrict__ batch,
                            float* sums, int* cnts, int N){
  int lane = threadIdx.x;  // block of 64
  int s = blockIdx.x * 128;
  if (s >= N) return;
  int e = min(s + 128, N);
  float acc = 0.f;
  int cnt = 0;
  int cur = batch[s];
  for (int n = s; n < e; n++){
    int g = batch[n];
    if (g != cur){
      atomicAdd(&sums[cur * 64 + lane], acc);
      if (lane == 0) atomicAdd(&cnts[cur], cnt);
      acc = 0.f; cnt = 0; cur = g;
    }
    acc += f[(size_t)n * 64 + lane];
    cnt++;
  }
  atomicAdd(&sums[cur * 64 + lane], acc);
  if (lane == 0) atomicAdd(&cnts[cur], cnt);
}

__global__ void final_kernel(const float* __restrict__ sums, const int* __restrict__ cnts,
                             const float* __restrict__ linW, const float* __restrict__ linb,
                             float* __restrict__ out){
  int t = threadIdx.x;
  if (t >= 640) return;
  int g = t / 10, o = t % 10;
  float c = fmaxf((float)cnts[g], 1.f);
  float acc = 0.f;
#pragma unroll
  for (int k = 0; k < 64; k++) acc += sums[g * 64 + k] * linW[k * 10 + o];
  out[t] = acc / c + linb[o];
}

// ---------------- launch ----------------
extern "C" void kernel_launch(void* const* d_in, const int* in_sizes, int n_in,
                              void* d_out, int out_size, void* d_ws, size_t ws_size,
                              hipStream_t stream) {
  const float* x     = (const float*)d_in[0];
  const int*   ei    = (const int*)  d_in[1];
  const int*   batch = (const int*)  d_in[2];
  const float* W1    = (const float*)d_in[3];
  const float* b1    = (const float*)d_in[4];
  const float* asrc1 = (const float*)d_in[5];
  const float* adst1 = (const float*)d_in[6];
  const float* W2    = (const float*)d_in[7];
  const float* b2    = (const float*)d_in[8];
  const float* asrc2 = (const float*)d_in[9];
  const float* adst2 = (const float*)d_in[10];
  const float* W3    = (const float*)d_in[11];
  const float* b3    = (const float*)d_in[12];
  const float* asrc3 = (const float*)d_in[13];
  const float* adst3 = (const float*)d_in[14];
  const float* linW  = (const float*)d_in[15];
  const float* linb  = (const float*)d_in[16];

  const int N = in_sizes[0] / 128;   // 50000
  const int E = in_sizes[1] / 2;     // 600000
  const int Etot = E + N;
  const int G = 64;
  const int* src = ei;
  const int* dst = ei + E;

  char* p = (char*)d_ws;
  auto carve = [&](size_t bytes) -> char* {
    char* r = p;
    p += (bytes + 255) & ~(size_t)255;
    return r;
  };
  u16*   xb       = (u16*)  carve((size_t)N * 128 * 2);
  u16*   w1t      = (u16*)  carve((size_t)256 * 128 * 2);
  u16*   w2t      = (u16*)  carve((size_t)256 * 256 * 2);
  u16*   w3t      = (u16*)  carve((size_t)64 * 256 * 2);
  u16*   hb       = (u16*)  carve((size_t)N * 256 * 2);
  u16*   featb    = (u16*)  carve((size_t)N * 256 * 2);
  float* out3     = (float*)carve((size_t)N * 64 * 4);
  float* als      = (float*)carve((size_t)N * 4 * 4);
  float* ald      = (float*)carve((size_t)N * 4 * 4);
  int*   counts   = (int*)  carve((size_t)N * 4);
  int*   row_ptr  = (int*)  carve((size_t)(N + 1) * 4);
  int*   cursor   = (int*)  carve((size_t)N * 4);
  int*   edge_src = (int*)  carve((size_t)Etot * 4);
  int*   bsums    = (int*)  carve(256 * 4);
  int*   total    = (int*)  carve(256);
  float* sums     = (float*)carve((size_t)G * 64 * 4);
  int*   cnts     = (int*)  carve((size_t)G * 4);

  const int nb = (N + 255) / 256;   // 196

  // ---- conversions ----
  cvt_bf16_kernel<<<(N * 128 / 4 + 255) / 256, 256, 0, stream>>>(x, xb, N * 128 / 4);
  transpose_w_kernel<<<(128 * 256 + 255) / 256, 256, 0, stream>>>(W1, w1t, 128, 256);
  transpose_w_kernel<<<(256 * 256 + 255) / 256, 256, 0, stream>>>(W2, w2t, 256, 256);
  transpose_w_kernel<<<(256 * 64 + 255) / 256, 256, 0, stream>>>(W3, w3t, 256, 64);

  // ---- CSR build ----
  hipMemsetAsync(counts, 0, (size_t)N * 4, stream);
  hist_kernel<<<(Etot + 255) / 256, 256, 0, stream>>>(dst, E, N, counts);
  scan_block_kernel<<<nb, 256, 0, stream>>>(counts, row_ptr, bsums, N);
  scan_sums_kernel<<<1, 256, 0, stream>>>(bsums, nb, total);
  scan_add_kernel<<<nb, 256, 0, stream>>>(row_ptr, cursor, bsums, total, N);
  scatter_kernel<<<(Etot + 255) / 256, 256, 0, stream>>>(src, dst, E, N, cursor, edge_src);

  const int nby = (N + 127) / 128;  // 391 row tiles
  const int wpn_grid = (N + 3) / 4; // wave-per-node grids

  // ---- layer 1: 128 -> 4x64 ----
  gemm_mfma<128><<<dim3(2, nby), 256, 0, stream>>>(xb, w1t, hb, N, 128, 256);
  al_kernel<4><<<wpn_grid, 256, 0, stream>>>(hb, asrc1, adst1, als, ald, N);
  agg4_kernel<true><<<wpn_grid, 256, 0, stream>>>(hb, als, ald, row_ptr, edge_src, b1, featb, N);

  // ---- layer 2: 256 -> 4x64 ----
  gemm_mfma<128><<<dim3(2, nby), 256, 0, stream>>>(featb, w2t, hb, N, 256, 256);
  al_kernel<4><<<wpn_grid, 256, 0, stream>>>(hb, asrc2, adst2, als, ald, N);
  agg4_kernel<true><<<wpn_grid, 256, 0, stream>>>(hb, als, ald, row_ptr, edge_src, b2, featb, N);

  // ---- layer 3: 256 -> 1x64 ----
  gemm_mfma<64><<<dim3(1, nby), 256, 0, stream>>>(featb, w3t, hb, N, 256, 64);
  al_kernel<1><<<wpn_grid, 256, 0, stream>>>(hb, asrc3, adst3, als, ald, N);
  agg1_kernel<<<wpn_grid, 256, 0, stream>>>(hb, als, ald, row_ptr, edge_src, b3, out3, N);

  // ---- pool + final linear ----
  hipMemsetAsync(sums, 0, (size_t)G * 64 * 4, stream);
  hipMemsetAsync(cnts, 0, (size_t)G * 4, stream);
  pool_kernel<<<(N + 127) / 128, 64, 0, stream>>>(out3, batch, sums, cnts, N);
  final_kernel<<<1, 640, 0, stream>>>(sums, cnts, linW, linb, (float*)d_out);
}

// Round 4
// 416.345 us; speedup vs baseline: 2.1895x; 1.0397x over previous
//
#include <hip/hip_runtime.h>
#include <hip/hip_bf16.h>
#include <math.h>

#define NEG_SLOPE 0.2f

typedef short short8 __attribute__((ext_vector_type(8)));
typedef float f32x4 __attribute__((ext_vector_type(4)));
typedef unsigned int u32;
typedef unsigned short u16;

__device__ __forceinline__ float lrelu(float x){ return x > 0.f ? x : NEG_SLOPE * x; }
__device__ __forceinline__ float elu_f(float x){ return x > 0.f ? x : __expf(x) - 1.f; }
__device__ __forceinline__ float bf2f(u16 u){ return __uint_as_float(((u32)u) << 16); }
__device__ __forceinline__ u16 f2bf(float f){
  __hip_bfloat16 h = __float2bfloat16(f);
  return *(u16*)&h;
}

// ---------------- fused prep: x->bf16 + 3 weight transposes ----------------
__global__ void prep_kernel(const float* __restrict__ x, u16* __restrict__ xb, int n4,
                            const float* __restrict__ W1, u16* __restrict__ w1t,
                            const float* __restrict__ W2, u16* __restrict__ w2t,
                            const float* __restrict__ W3, u16* __restrict__ w3t){
  int i = blockIdx.x * 256 + threadIdx.x;
  if (i < n4){
    float4 v = ((const float4*)x)[i];
    ushort4 o;
    o.x = f2bf(v.x); o.y = f2bf(v.y); o.z = f2bf(v.z); o.w = f2bf(v.w);
    ((ushort4*)xb)[i] = o;
    return;
  }
  int t = i - n4;
  if (t < 128 * 256){              // W1 [128][256] -> w1t [256][128]
    int k = t >> 8, m = t & 255;
    w1t[m * 128 + k] = f2bf(W1[t]);
    return;
  }
  t -= 128 * 256;
  if (t < 256 * 256){              // W2 [256][256] -> w2t [256][256]
    int k = t >> 8, m = t & 255;
    w2t[m * 256 + k] = f2bf(W2[t]);
    return;
  }
  t -= 256 * 256;
  if (t < 256 * 64){               // W3 [256][64] -> w3t [64][256]
    int k = t >> 6, m = t & 63;
    w3t[m * 256 + k] = f2bf(W3[t]);
  }
}

// ---------------- CSR build ----------------
__global__ void hist_kernel(const int* __restrict__ dst, int E, int N, int* counts){
  int i = blockIdx.x * 256 + threadIdx.x;
  if (i < E + N){
    int d = (i < E) ? dst[i] : (i - E);
    atomicAdd(&counts[d], 1);
  }
}

__global__ void scan_block_kernel(const int* __restrict__ counts, int* __restrict__ rp,
                                  int* __restrict__ bsums, int N){
  __shared__ int s[256];
  int i = blockIdx.x * 256 + threadIdx.x;
  int v = (i < N) ? counts[i] : 0;
  s[threadIdx.x] = v;
  __syncthreads();
  for (int off = 1; off < 256; off <<= 1){
    int t = (threadIdx.x >= off) ? s[threadIdx.x - off] : 0;
    __syncthreads();
    s[threadIdx.x] += t;
    __syncthreads();
  }
  if (i < N) rp[i] = s[threadIdx.x] - v;
  if (threadIdx.x == 255) bsums[blockIdx.x] = s[255];
}

__global__ void scan_sums_kernel(int* bsums, int nb, int* total){
  __shared__ int s[256];
  int v = (threadIdx.x < nb) ? bsums[threadIdx.x] : 0;
  s[threadIdx.x] = v;
  __syncthreads();
  for (int off = 1; off < 256; off <<= 1){
    int t = (threadIdx.x >= off) ? s[threadIdx.x - off] : 0;
    __syncthreads();
    s[threadIdx.x] += t;
    __syncthreads();
  }
  if (threadIdx.x < nb) bsums[threadIdx.x] = s[threadIdx.x] - v;
  if (threadIdx.x == 255) *total = s[255];
}

__global__ void scan_add_kernel(int* __restrict__ rp, int* __restrict__ cur,
                                const int* __restrict__ bsums,
                                const int* __restrict__ total, int N){
  int i = blockIdx.x * 256 + threadIdx.x;
  if (i < N){
    int v = rp[i] + bsums[blockIdx.x];
    rp[i] = v;
    cur[i] = v;
  }
  if (i == 0) rp[N] = *total;
}

__global__ void scatter_kernel(const int* __restrict__ src, const int* __restrict__ dst,
                               int E, int N, int* cursor, int* __restrict__ edge_src){
  int i = blockIdx.x * 256 + threadIdx.x;
  if (i < E + N){
    int s, d;
    if (i < E){ s = src[i]; d = dst[i]; }
    else      { s = i - E;  d = i - E;  }
    int pos = atomicAdd(&cursor[d], 1);
    edge_src[pos] = s;
  }
}

// ---------------- bf16 MFMA GEMM + fused attention logits ----------------
// C[N,M] = A[N,K] @ Bt[M,K]^T; als/ald[n,h] = sum_c C[n,h*64+c]*a{src,dst}[h,c]
template<int BN>
__global__ __launch_bounds__(256) void gemm_mfma(const u16* __restrict__ A,
                                                 const u16* __restrict__ Bt,
                                                 u16* __restrict__ C,
                                                 const float* __restrict__ asrc,
                                                 const float* __restrict__ adst,
                                                 float* __restrict__ als,
                                                 float* __restrict__ ald,
                                                 int N, int K, int M){
  constexpr int BM = 128;
  constexpr int MI = (BN == 128) ? 4 : 2;
  constexpr int SB = BN * 8 / 256;
  constexpr int HH = (BN == 128) ? 4 : 1;   // heads in M
  __shared__ short As[8][BM][8];
  __shared__ short Bs[8][BN][8];
  const int tid = threadIdx.x;
  const int w = tid >> 6, lane = tid & 63;
  const int quad = lane >> 4, l16 = lane & 15;
  const int row0 = blockIdx.y * BM, col0 = blockIdx.x * BN;
  const int wrow = (BN == 128) ? (w >> 1) * 64 : w * 32;
  const int wcol = (BN == 128) ? (w & 1) * 64 : 0;

  f32x4 acc[MI][4];
#pragma unroll
  for (int i = 0; i < MI; i++)
#pragma unroll
    for (int j = 0; j < 4; j++) acc[i][j] = (f32x4){0.f, 0.f, 0.f, 0.f};

  for (int k0 = 0; k0 < K; k0 += 64){
    __syncthreads();
#pragma unroll
    for (int q = 0; q < 4; q++){
      int lb = q * 256 + w * 64;      // wave-uniform
      int li = lb + lane;
      int c = li >> 7, r = li & 127;
      int grow = min(row0 + r, N - 1);
      const u16* gp = A + (size_t)grow * K + k0 + c * 8;
      __builtin_amdgcn_global_load_lds((const __attribute__((address_space(1))) void*)gp,
                                       (__attribute__((address_space(3))) void*)((char*)&As[0][0][0] + (size_t)lb * 16),
                                       16, 0, 0);
    }
#pragma unroll
    for (int q = 0; q < SB; q++){
      int lb = q * 256 + w * 64;
      int li = lb + lane;
      int c = li / BN, n = li % BN;
      const u16* gp = Bt + (size_t)(col0 + n) * K + k0 + c * 8;
      __builtin_amdgcn_global_load_lds((const __attribute__((address_space(1))) void*)gp,
                                       (__attribute__((address_space(3))) void*)((char*)&Bs[0][0][0] + (size_t)lb * 16),
                                       16, 0, 0);
    }
    __syncthreads();
#pragma unroll
    for (int ks = 0; ks < 2; ks++){
      short8 a[MI], b[4];
#pragma unroll
      for (int i = 0; i < MI; i++) a[i] = *(const short8*)&As[ks * 4 + quad][wrow + i * 16 + l16][0];
#pragma unroll
      for (int j = 0; j < 4; j++)  b[j] = *(const short8*)&Bs[ks * 4 + quad][wcol + j * 16 + l16][0];
#pragma unroll
      for (int i = 0; i < MI; i++)
#pragma unroll
        for (int j = 0; j < 4; j++)
          acc[i][j] = __builtin_amdgcn_mfma_f32_16x16x32_bf16(a[i], b[j], acc[i][j], 0, 0, 0);
    }
  }

  // wave covers cols [col0+wcol, +64) = one head; per-row dot for al
  const int head = (col0 + wcol) >> 6;
  float avs[4], avd[4];
#pragma unroll
  for (int j = 0; j < 4; j++){
    int c = j * 16 + l16;
    avs[j] = asrc[head * 64 + c];
    avd[j] = adst[head * 64 + c];
  }

#pragma unroll
  for (int i = 0; i < MI; i++){
#pragma unroll
    for (int rr = 0; rr < 4; rr++){
      int row = row0 + wrow + i * 16 + quad * 4 + rr;
      float ps = acc[i][0][rr] * avs[0] + acc[i][1][rr] * avs[1]
               + acc[i][2][rr] * avs[2] + acc[i][3][rr] * avs[3];
      float pd = acc[i][0][rr] * avd[0] + acc[i][1][rr] * avd[1]
               + acc[i][2][rr] * avd[2] + acc[i][3][rr] * avd[3];
#pragma unroll
      for (int off = 8; off > 0; off >>= 1){
        ps += __shfl_xor(ps, off);
        pd += __shfl_xor(pd, off);
      }
      if (row < N){
#pragma unroll
        for (int j = 0; j < 4; j++)
          C[(size_t)row * M + col0 + wcol + j * 16 + l16] = f2bf(acc[i][j][rr]);
        if (l16 == 0){
          als[(size_t)row * HH + head] = ps;
          ald[(size_t)row * HH + head] = pd;
        }
      }
    }
  }
}

// ---------------- H=4 aggregate: lane-parallel ex precompute + broadcast loop ----------------
template<bool OBF>
__global__ __launch_bounds__(256) void agg4_kernel(const u16* __restrict__ hb,
    const float* __restrict__ als, const float* __restrict__ ald,
    const int* __restrict__ row_ptr, const int* __restrict__ edge_src,
    const float* __restrict__ bias, void* __restrict__ outv, int N){
  __shared__ float lex[4][256];
  __shared__ int lu[4][64];
  int wslot = threadIdx.x >> 6;
  int node = (blockIdx.x * 256 + threadIdx.x) >> 6;
  int lane = threadIdx.x & 63;
  if (node >= N) return;
  int beg = row_ptr[node], end = row_ptr[node + 1];
  int deg = end - beg;
  float4 t4 = *(const float4*)(ald + node * 4);

  float m0 = -1e30f, m1 = -1e30f, m2 = -1e30f, m3 = -1e30f;
  int u_mine = 0;
  float e0 = -1e30f, e1 = -1e30f, e2 = -1e30f, e3 = -1e30f;
  for (int c0 = 0; c0 < deg; c0 += 64){
    int j = c0 + lane;
    bool v = j < deg;
    int u = v ? edge_src[beg + j] : 0;
    float4 s = v ? *(const float4*)(als + (size_t)u * 4)
                 : make_float4(-1e30f, -1e30f, -1e30f, -1e30f);
    float f0 = lrelu(s.x + t4.x), f1 = lrelu(s.y + t4.y);
    float f2 = lrelu(s.z + t4.z), f3 = lrelu(s.w + t4.w);
    m0 = fmaxf(m0, f0); m1 = fmaxf(m1, f1);
    m2 = fmaxf(m2, f2); m3 = fmaxf(m3, f3);
    if (c0 == 0){ u_mine = u; e0 = f0; e1 = f1; e2 = f2; e3 = f3; }
  }
#pragma unroll
  for (int off = 32; off > 0; off >>= 1){
    m0 = fmaxf(m0, __shfl_xor(m0, off)); m1 = fmaxf(m1, __shfl_xor(m1, off));
    m2 = fmaxf(m2, __shfl_xor(m2, off)); m3 = fmaxf(m3, __shfl_xor(m3, off));
  }
  const int hh = lane >> 4;
  float a0 = 0.f, a1 = 0.f, a2 = 0.f, a3 = 0.f, denom = 0.f;
  const u16* hbl = hb + lane * 4;

  for (int c0 = 0; c0 < deg; c0 += 64){
    int cnt = min(64, deg - c0);
    int u; float f0, f1, f2, f3;
    if (c0 == 0){ u = u_mine; f0 = e0; f1 = e1; f2 = e2; f3 = e3; }
    else {
      int j = c0 + lane;
      bool v = j < deg;
      u = v ? edge_src[beg + j] : 0;
      float4 s = v ? *(const float4*)(als + (size_t)u * 4)
                   : make_float4(-1e30f, -1e30f, -1e30f, -1e30f);
      f0 = lrelu(s.x + t4.x); f1 = lrelu(s.y + t4.y);
      f2 = lrelu(s.z + t4.z); f3 = lrelu(s.w + t4.w);
    }
    float4 exv;
    exv.x = __expf(f0 - m0); exv.y = __expf(f1 - m1);
    exv.z = __expf(f2 - m2); exv.w = __expf(f3 - m3);
    *(float4*)&lex[wslot][lane * 4] = exv;
    lu[wslot][lane] = u;
    asm volatile("s_waitcnt lgkmcnt(0)" ::: "memory");
#pragma unroll 4
    for (int j = 0; j < cnt; j++){
      float ex = lex[wslot][j * 4 + hh];   // broadcast ds_read
      int uu = lu[wslot][j];               // broadcast ds_read
      uint2 t = *(const uint2*)(hbl + (size_t)uu * 256);
      denom += ex;
      a0 += ex * __uint_as_float((t.x & 0xffffu) << 16);
      a1 += ex * __uint_as_float(t.x & 0xffff0000u);
      a2 += ex * __uint_as_float((t.y & 0xffffu) << 16);
      a3 += ex * __uint_as_float(t.y & 0xffff0000u);
    }
    asm volatile("" ::: "memory");
  }
  float inv = 1.f / (denom + 1e-16f);
  int ch = lane * 4;
  float o0 = elu_f(a0 * inv + bias[ch]);
  float o1 = elu_f(a1 * inv + bias[ch + 1]);
  float o2 = elu_f(a2 * inv + bias[ch + 2]);
  float o3 = elu_f(a3 * inv + bias[ch + 3]);
  if (OBF){
    uint2 o;
    o.x = (u32)f2bf(o0) | ((u32)f2bf(o1) << 16);
    o.y = (u32)f2bf(o2) | ((u32)f2bf(o3) << 16);
    ((uint2*)outv)[(size_t)node * 64 + lane] = o;
  } else {
    *(float4*)((float*)outv + (size_t)node * 256 + ch) = make_float4(o0, o1, o2, o3);
  }
}

// ---------------- H=1 aggregate: 4 edges / iteration ----------------
__global__ __launch_bounds__(256) void agg1_kernel(const u16* __restrict__ hb,
    const float* __restrict__ als, const float* __restrict__ ald,
    const int* __restrict__ row_ptr, const int* __restrict__ edge_src,
    const float* __restrict__ bias, float* __restrict__ out, int N){
  __shared__ float lex[4][64];
  __shared__ int lu[4][64];
  int wslot = threadIdx.x >> 6;
  int node = (blockIdx.x * 256 + threadIdx.x) >> 6;
  int lane = threadIdx.x & 63;
  if (node >= N) return;
  int beg = row_ptr[node], end = row_ptr[node + 1];
  int deg = end - beg;
  float adv = ald[node];
  float m = -1e30f;
  int u_mine = 0; float e_mine = -1e30f;
  for (int c0 = 0; c0 < deg; c0 += 64){
    int j = c0 + lane;
    bool v = j < deg;
    int u = v ? edge_src[beg + j] : 0;
    float e = v ? lrelu(als[u] + adv) : -1e30f;
    m = fmaxf(m, e);
    if (c0 == 0){ u_mine = u; e_mine = e; }
  }
#pragma unroll
  for (int off = 32; off > 0; off >>= 1) m = fmaxf(m, __shfl_xor(m, off));
  int eo = lane >> 4;           // edge offset 0..3
  int chb = (lane & 15) * 4;    // 4 channels per lane
  float a0 = 0.f, a1 = 0.f, a2 = 0.f, a3 = 0.f, denom = 0.f;
  for (int c0 = 0; c0 < deg; c0 += 64){
    int cnt = min(64, deg - c0);
    int u; float e;
    if (c0 == 0){ u = u_mine; e = e_mine; }
    else {
      int j = c0 + lane;
      bool v = j < deg;
      u = v ? edge_src[beg + j] : 0;
      e = v ? lrelu(als[u] + adv) : -1e30f;
    }
    lex[wslot][lane] = __expf(e - m);
    lu[wslot][lane] = u;
    asm volatile("s_waitcnt lgkmcnt(0)" ::: "memory");
#pragma unroll 4
    for (int j = 0; j < cnt; j += 4){
      int jj = j + eo;
      bool valid = jj < cnt;
      float ex = valid ? lex[wslot][jj] : 0.f;
      int uu = lu[wslot][jj];
      uint2 t = *(const uint2*)(hb + (size_t)uu * 64 + chb);
      denom += ex;
      a0 += ex * __uint_as_float((t.x & 0xffffu) << 16);
      a1 += ex * __uint_as_float(t.x & 0xffff0000u);
      a2 += ex * __uint_as_float((t.y & 0xffffu) << 16);
      a3 += ex * __uint_as_float(t.y & 0xffff0000u);
    }
    asm volatile("" ::: "memory");
  }
#pragma unroll
  for (int off = 16; off < 64; off <<= 1){
    denom += __shfl_xor(denom, off);
    a0 += __shfl_xor(a0, off); a1 += __shfl_xor(a1, off);
    a2 += __shfl_xor(a2, off); a3 += __shfl_xor(a3, off);
  }
  if (eo == 0){
    float inv = 1.f / (denom + 1e-16f);
    float o0 = elu_f(a0 * inv + bias[chb]);
    float o1 = elu_f(a1 * inv + bias[chb + 1]);
    float o2 = elu_f(a2 * inv + bias[chb + 2]);
    float o3 = elu_f(a3 * inv + bias[chb + 3]);
    *(float4*)(out + (size_t)node * 64 + chb) = make_float4(o0, o1, o2, o3);
  }
}

// ---------------- pooling (batch sorted) ----------------
__global__ void pool_kernel(const float* __restrict__ f, const int* __restrict__ batch,
                            float* sums, int* cnts, int N){
  int lane = threadIdx.x;  // block of 64
  int s = blockIdx.x * 128;
  if (s >= N) return;
  int e = min(s + 128, N);
  float acc = 0.f;
  int cnt = 0;
  int cur = batch[s];
  for (int n = s; n < e; n++){
    int g = batch[n];
    if (g != cur){
      atomicAdd(&sums[cur * 64 + lane], acc);
      if (lane == 0) atomicAdd(&cnts[cur], cnt);
      acc = 0.f; cnt = 0; cur = g;
    }
    acc += f[(size_t)n * 64 + lane];
    cnt++;
  }
  atomicAdd(&sums[cur * 64 + lane], acc);
  if (lane == 0) atomicAdd(&cnts[cur], cnt);
}

__global__ void final_kernel(const float* __restrict__ sums, const int* __restrict__ cnts,
                             const float* __restrict__ linW, const float* __restrict__ linb,
                             float* __restrict__ out){
  int t = threadIdx.x;
  if (t >= 640) return;
  int g = t / 10, o = t % 10;
  float c = fmaxf((float)cnts[g], 1.f);
  float acc = 0.f;
#pragma unroll
  for (int k = 0; k < 64; k++) acc += sums[g * 64 + k] * linW[k * 10 + o];
  out[t] = acc / c + linb[o];
}

// ---------------- launch ----------------
extern "C" void kernel_launch(void* const* d_in, const int* in_sizes, int n_in,
                              void* d_out, int out_size, void* d_ws, size_t ws_size,
                              hipStream_t stream) {
  const float* x     = (const float*)d_in[0];
  const int*   ei    = (const int*)  d_in[1];
  const int*   batch = (const int*)  d_in[2];
  const float* W1    = (const float*)d_in[3];
  const float* b1    = (const float*)d_in[4];
  const float* asrc1 = (const float*)d_in[5];
  const float* adst1 = (const float*)d_in[6];
  const float* W2    = (const float*)d_in[7];
  const float* b2    = (const float*)d_in[8];
  const float* asrc2 = (const float*)d_in[9];
  const float* adst2 = (const float*)d_in[10];
  const float* W3    = (const float*)d_in[11];
  const float* b3    = (const float*)d_in[12];
  const float* asrc3 = (const float*)d_in[13];
  const float* adst3 = (const float*)d_in[14];
  const float* linW  = (const float*)d_in[15];
  const float* linb  = (const float*)d_in[16];

  const int N = in_sizes[0] / 128;   // 50000
  const int E = in_sizes[1] / 2;     // 600000
  const int Etot = E + N;
  const int G = 64;
  const int* src = ei;
  const int* dst = ei + E;

  char* p = (char*)d_ws;
  auto carve = [&](size_t bytes) -> char* {
    char* r = p;
    p += (bytes + 255) & ~(size_t)255;
    return r;
  };
  u16*   xb       = (u16*)  carve((size_t)N * 128 * 2);
  u16*   w1t      = (u16*)  carve((size_t)256 * 128 * 2);
  u16*   w2t      = (u16*)  carve((size_t)256 * 256 * 2);
  u16*   w3t      = (u16*)  carve((size_t)64 * 256 * 2);
  u16*   hb       = (u16*)  carve((size_t)N * 256 * 2);
  u16*   featb    = (u16*)  carve((size_t)N * 256 * 2);
  float* out3     = (float*)carve((size_t)N * 64 * 4);
  float* als      = (float*)carve((size_t)N * 4 * 4);
  float* ald      = (float*)carve((size_t)N * 4 * 4);
  int*   counts   = (int*)  carve((size_t)N * 4);
  int*   row_ptr  = (int*)  carve((size_t)(N + 1) * 4);
  int*   cursor   = (int*)  carve((size_t)N * 4);
  int*   edge_src = (int*)  carve((size_t)Etot * 4);
  int*   bsums    = (int*)  carve(256 * 4);
  int*   total    = (int*)  carve(256);
  float* sums     = (float*)carve((size_t)G * 64 * 4);
  int*   cnts     = (int*)  carve((size_t)G * 4);

  const int nb = (N + 255) / 256;   // 196
  const int n4 = N * 128 / 4;
  const int prep_items = n4 + 128 * 256 + 256 * 256 + 256 * 64;

  // ---- prep (cvt + transposes) ----
  prep_kernel<<<(prep_items + 255) / 256, 256, 0, stream>>>(x, xb, n4, W1, w1t, W2, w2t, W3, w3t);

  // ---- CSR build ----
  hipMemsetAsync(counts, 0, (size_t)N * 4, stream);
  hist_kernel<<<(Etot + 255) / 256, 256, 0, stream>>>(dst, E, N, counts);
  scan_block_kernel<<<nb, 256, 0, stream>>>(counts, row_ptr, bsums, N);
  scan_sums_kernel<<<1, 256, 0, stream>>>(bsums, nb, total);
  scan_add_kernel<<<nb, 256, 0, stream>>>(row_ptr, cursor, bsums, total, N);
  scatter_kernel<<<(Etot + 255) / 256, 256, 0, stream>>>(src, dst, E, N, cursor, edge_src);

  const int nby = (N + 127) / 128;  // 391 row tiles
  const int wpn_grid = (N + 3) / 4; // wave-per-node grids

  // ---- layer 1: 128 -> 4x64 ----
  gemm_mfma<128><<<dim3(2, nby), 256, 0, stream>>>(xb, w1t, hb, asrc1, adst1, als, ald, N, 128, 256);
  agg4_kernel<true><<<wpn_grid, 256, 0, stream>>>(hb, als, ald, row_ptr, edge_src, b1, featb, N);

  // ---- layer 2: 256 -> 4x64 ----
  gemm_mfma<128><<<dim3(2, nby), 256, 0, stream>>>(featb, w2t, hb, asrc2, adst2, als, ald, N, 256, 256);
  agg4_kernel<true><<<wpn_grid, 256, 0, stream>>>(hb, als, ald, row_ptr, edge_src, b2, featb, N);

  // ---- layer 3: 256 -> 1x64 ----
  gemm_mfma<64><<<dim3(1, nby), 256, 0, stream>>>(featb, w3t, hb, asrc3, adst3, als, ald, N, 256, 64);
  agg1_kernel<<<wpn_grid, 256, 0, stream>>>(hb, als, ald, row_ptr, edge_src, b3, out3, N);

  // ---- pool + final linear ----
  hipMemsetAsync(sums, 0, (size_t)G * 64 * 4, stream);
  hipMemsetAsync(cnts, 0, (size_t)G * 4, stream);
  pool_kernel<<<(N + 127) / 128, 64, 0, stream>>>(out3, batch, sums, cnts, N);
  final_kernel<<<1, 640, 0, stream>>>(sums, cnts, linW, linb, (float*)d_out);
}